// Round 1
// baseline (706.128 us; speedup 1.0000x reference)
//
#include <hip/hip_runtime.h>
#include <stdint.h>

#define N_BOXES 6000
#define NT 94            // ceil(6000/64) tiles of 64
#define R  NT            // u64 words per mask row
#define IOU_THR 0.5f
#define CONF_THR 0.6f

typedef unsigned long long u64;

// ---- kernel 1: sort keys --------------------------------------------------
// scores are uniform [0,1) -> nonnegative -> raw bits are monotone in value.
// key = (~bits << 32) | index  => ascending u64 sort == descending score,
// ties broken by ascending original index (matches JAX stable argsort(-s)).
__global__ void k_keys(const float* __restrict__ scores, u64* __restrict__ keys) {
    int i = blockIdx.x * blockDim.x + threadIdx.x;
    if (i < N_BOXES) {
        unsigned inv = ~__float_as_uint(scores[i]);
        keys[i] = ((u64)inv << 32) | (unsigned)i;
    }
}

// ---- kernel 2: rank (counting sort) + gather sorted boxes -----------------
__global__ void k_rank(const u64* __restrict__ keys, const float4* __restrict__ boxes,
                       int* __restrict__ sidx, float4* __restrict__ sboxes) {
    __shared__ u64 kt[256];
    int i = blockIdx.x * blockDim.x + threadIdx.x;
    u64 mykey = (i < N_BOXES) ? keys[i] : ~0ull;
    int r = 0;
    for (int base = 0; base < N_BOXES; base += 256) {
        int j = base + threadIdx.x;
        kt[threadIdx.x] = (j < N_BOXES) ? keys[j] : ~0ull;
        __syncthreads();
        int lim = min(256, N_BOXES - base);
        for (int jj = 0; jj < lim; ++jj)
            r += (kt[jj] < mykey) ? 1 : 0;
        __syncthreads();
    }
    if (i < N_BOXES) {          // keys are all distinct -> r is a permutation
        sidx[r] = i;
        sboxes[r] = boxes[i];
    }
}

// ---- kernel 3: pairwise IoU suppression bitmask ---------------------------
// block = 1 wave (64 lanes). block (ct, rt): lane = column box, loop rows.
// mask[row][ct] bit b set iff iou(row, ct*64+b) > 0.5 and col > row.
__global__ void k_mask(const float4* __restrict__ sboxes, u64* __restrict__ mask) {
    int ct = blockIdx.x, rt = blockIdx.y;
    if (ct < rt) return;
    int lane = threadIdx.x;
    __shared__ float4 rb[64];
    int row0 = rt * 64;
    int rows = min(64, N_BOXES - row0);
    if (lane < rows) rb[lane] = sboxes[row0 + lane];
    __syncthreads();
    int j = ct * 64 + lane;
    bool jvalid = (j < N_BOXES);
    float4 cb = make_float4(0.f, 0.f, 1.f, 1.f);
    if (jvalid) cb = sboxes[j];
    float carea = (cb.z - cb.x) * (cb.w - cb.y);
    for (int i = 0; i < rows; ++i) {
        float4 rbx = rb[i];
        float rarea = (rbx.z - rbx.x) * (rbx.w - rbx.y);
        // identical f32 op order as the reference (_pairwise_iou)
        float iw = fmaxf(fminf(rbx.z, cb.z) - fmaxf(rbx.x, cb.x), 0.f);
        float ih = fmaxf(fminf(rbx.w, cb.w) - fmaxf(rbx.y, cb.y), 0.f);
        float inter = iw * ih;
        float iou = inter / ((rarea + carea) - inter);
        int row = row0 + i;
        bool pred = jvalid && (j > row) && (iou > IOU_THR);
        u64 bal = __ballot(pred);
        if (lane == (i & 63)) mask[(u64)row * R + ct] = bal;
    }
}

// ---- kernel 4: greedy scan (single block) ---------------------------------
__global__ void __launch_bounds__(1024) k_scan(const u64* __restrict__ mask,
                                               u64* __restrict__ keepbits) {
    __shared__ u64 removed[NT];
    __shared__ u64 keepw_s[NT];
    __shared__ u64 diag[64];
    int tid = threadIdx.x;
    if (tid < NT) removed[tid] = 0;
    __syncthreads();
    for (int t = 0; t < NT; ++t) {
        int row0 = t * 64;
        int rows = min(64, N_BOXES - row0);
        if (tid < 64) diag[tid] = (tid < rows) ? mask[(u64)(row0 + tid) * R + t] : 0ull;
        __syncthreads();
        if (tid == 0) {
            // the only true sequential dependency: resolve the diagonal word
            u64 cur = removed[t], kw = 0;
            for (int i = 0; i < rows; ++i) {
                if (!((cur >> i) & 1ull)) { kw |= 1ull << i; cur |= diag[i]; }
            }
            removed[t] = cur;
            keepw_s[t] = kw;
        }
        __syncthreads();
        u64 kw = keepw_s[t];
        int nw = NT - 1 - t;
        if (nw > 0 && kw != 0ull) {
            int rg = tid >> 7;       // 8 row-groups of 8 rows
            int wl = tid & 127;      // word lane (covers up to 128 >= 93 words)
            if (wl < nw) {
                int w = t + 1 + wl;
                u64 acc = 0;
                int ibase = rg * 8;
                for (int ii = 0; ii < 8; ++ii) {
                    int i = ibase + ii;
                    if ((kw >> i) & 1ull) acc |= mask[(u64)(row0 + i) * R + w];
                }
                if (acc) atomicOr(&removed[w], acc);
            }
        }
        __syncthreads();
    }
    if (tid < NT) keepbits[tid] = keepw_s[tid];
}

// ---- kernel 5: epilogue ---------------------------------------------------
__global__ void k_out(const int* __restrict__ sidx, const float* __restrict__ scores,
                      const u64* __restrict__ keepbits, float* __restrict__ out) {
    int p = blockIdx.x * blockDim.x + threadIdx.x;
    if (p < N_BOXES) {
        int orig = sidx[p];
        float s = scores[orig];
        bool k = (keepbits[p >> 6] >> (p & 63)) & 1ull;
        out[orig] = (k && (s >= CONF_THR)) ? s : 0.0f;  // writes ALL outputs (d_out is poisoned)
    }
}

extern "C" void kernel_launch(void* const* d_in, const int* in_sizes, int n_in,
                              void* d_out, int out_size, void* d_ws, size_t ws_size,
                              hipStream_t stream) {
    const float*  boxes  = (const float*)d_in[0];   // [6000,4]
    const float*  scores = (const float*)d_in[1];   // [6000]
    float* out = (float*)d_out;                     // [6000]

    // workspace layout (all 16B-aligned)
    char* ws = (char*)d_ws;
    u64*    mask     = (u64*)(ws);                       // 6000*94*8 = 4,512,000 B
    u64*    keys     = (u64*)(ws + 4512000);             // 48,000 B
    int*    sidx     = (int*)(ws + 4560000);             // 24,000 B
    float4* sboxes   = (float4*)(ws + 4584000);          // 96,000 B
    u64*    keepbits = (u64*)(ws + 4680000);             // 752 B

    k_keys<<<dim3((N_BOXES + 255) / 256), dim3(256), 0, stream>>>(scores, keys);
    k_rank<<<dim3((N_BOXES + 255) / 256), dim3(256), 0, stream>>>(keys, (const float4*)boxes, sidx, sboxes);
    k_mask<<<dim3(NT, NT), dim3(64), 0, stream>>>(sboxes, mask);
    k_scan<<<dim3(1), dim3(1024), 0, stream>>>(mask, keepbits);
    k_out<<<dim3((N_BOXES + 255) / 256), dim3(256), 0, stream>>>(sidx, scores, keepbits, out);
}

// Round 2
// 665.007 us; speedup vs baseline: 1.0618x; 1.0618x over previous
//
#include <hip/hip_runtime.h>
#include <stdint.h>

#define N_BOXES 6000
#define NT 94            // ceil(6000/64) tiles of 64
#define R  NT            // u64 words per mask row
#define IOU_THR 0.5f
#define CONF_THR 0.6f

typedef unsigned long long u64;

__device__ __forceinline__ u64 rdlane64(u64 v, int l) {
    unsigned lo = (unsigned)__builtin_amdgcn_readlane((int)(unsigned)v, l);
    unsigned hi = (unsigned)__builtin_amdgcn_readlane((int)(unsigned)(v >> 32), l);
    return ((u64)hi << 32) | lo;
}

// ---- kernel 1: keys + zero ranks ------------------------------------------
// scores uniform [0,1) -> raw float bits monotone. key = (~bits<<32)|index:
// ascending u64 == descending score, ties by ascending index (JAX stable argsort).
__global__ void k_prep(const float* __restrict__ scores, u64* __restrict__ keys,
                       int* __restrict__ rank) {
    int i = blockIdx.x * blockDim.x + threadIdx.x;
    if (i < N_BOXES) {
        unsigned inv = ~__float_as_uint(scores[i]);
        keys[i] = ((u64)inv << 32) | (unsigned)i;
        rank[i] = 0;
    }
}

// ---- kernel 2: partial rank counts (2D: 24 i-blocks x 8 j-segments) -------
__global__ void __launch_bounds__(256) k_count(const u64* __restrict__ keys,
                                               int* __restrict__ rank) {
    __shared__ u64 kt[750];
    const int tid = threadIdx.x;
    const int i = blockIdx.x * 256 + tid;
    const int j0 = blockIdx.y * 750;
    for (int k = tid; k < 750; k += 256) kt[k] = keys[j0 + k];
    __syncthreads();
    u64 mykey = (i < N_BOXES) ? keys[i] : 0ull;
    int cnt = 0;
#pragma unroll 10
    for (int jj = 0; jj < 750; ++jj) cnt += (kt[jj] < mykey) ? 1 : 0;
    if (i < N_BOXES) atomicAdd(&rank[i], cnt);
}

// ---- kernel 3: scatter into sorted order ----------------------------------
__global__ void k_scatter(const int* __restrict__ rank, const float4* __restrict__ boxes,
                          int* __restrict__ sidx, float4* __restrict__ sboxes) {
    int i = blockIdx.x * blockDim.x + threadIdx.x;
    if (i < N_BOXES) {
        int r = rank[i];              // keys distinct -> permutation
        sidx[r] = i;
        sboxes[r] = boxes[i];
    }
}

// ---- kernel 4: pairwise IoU suppression bitmask ---------------------------
// block = 1 wave. block (ct, rt): lane = column box, loop rows.
// mask[row][ct] bit b set iff iou(row, ct*64+b) > 0.5 and col > row.
// Diagonal words additionally written compactly to diagw[row].
__global__ void k_mask(const float4* __restrict__ sboxes, u64* __restrict__ mask,
                       u64* __restrict__ diagw) {
    int ct = blockIdx.x, rt = blockIdx.y;
    if (ct < rt) return;
    int lane = threadIdx.x;
    __shared__ float4 rb[64];
    int row0 = rt * 64;
    int rows = min(64, N_BOXES - row0);
    if (lane < rows) rb[lane] = sboxes[row0 + lane];
    __syncthreads();
    int j = ct * 64 + lane;
    bool jvalid = (j < N_BOXES);
    float4 cb = make_float4(0.f, 0.f, 1.f, 1.f);
    if (jvalid) cb = sboxes[j];
    float carea = (cb.z - cb.x) * (cb.w - cb.y);
    bool isdiag = (ct == rt);
    for (int i = 0; i < rows; ++i) {
        float4 rbx = rb[i];
        float rarea = (rbx.z - rbx.x) * (rbx.w - rbx.y);
        // identical f32 op order as the reference (_pairwise_iou)
        float iw = fmaxf(fminf(rbx.z, cb.z) - fmaxf(rbx.x, cb.x), 0.f);
        float ih = fmaxf(fminf(rbx.w, cb.w) - fmaxf(rbx.y, cb.y), 0.f);
        float inter = iw * ih;
        float iou = inter / ((rarea + carea) - inter);
        int row = row0 + i;
        bool pred = jvalid && (j > row) && (iou > IOU_THR);
        u64 bal = __ballot(pred);
        if (lane == (i & 63)) {
            mask[(u64)row * R + ct] = bal;
            if (isdiag) diagw[row] = bal;
        }
    }
}

// ---- kernel 5: greedy scan — ONE WAVE, register state, no barriers --------
// Lane l owns removed-words l and l+64. Diagonal resolve is a scalarized
// serial loop (the algorithm's true dependency); suppression ORs are batched
// 16 rows at a time into independent registers so each batch costs ONE
// memory-latency round instead of 16.
__global__ void __launch_bounds__(64) k_scan(const u64* __restrict__ mask,
                                             const u64* __restrict__ diagw,
                                             u64* __restrict__ keepbits) {
    const int lane = threadIdx.x;
    u64 r0 = 0, r1 = 0;                      // owned removed words: lane, lane+64
    const int w2 = (lane + 64 < NT) ? (lane + 64) : (NT - 1);  // clamped (garbage lanes unused)
    u64 d_cur = diagw[lane];                 // tile 0 diag words
    for (int t = 0; t < NT; ++t) {
        // prefetch next tile's diag words (independent of this tile's result)
        const int tn = (t + 1 < NT) ? (t + 1) : 0;
        u64 d_next = diagw[tn * 64 + lane];

        const int row0 = t * 64;
        const int rows = (N_BOXES - row0 >= 64) ? 64 : (N_BOXES - row0);
        const u64 valid = (rows == 64) ? ~0ull : ((1ull << rows) - 1ull);

        // ---- diagonal resolve (scalar chain: readlane + SALU) ----
        u64 curw = (t < 64) ? rdlane64(r0, t) : rdlane64(r1, t - 64);
        u64 cand = valid & ~curw;
        u64 kw = 0;
        while (cand) {
            int f = (int)__builtin_ctzll(cand);
            kw |= (1ull << f);
            u64 df = rdlane64(d_cur, f);     // suppressions by kept row f
            cand &= ~(df | (1ull << f));
        }
        if (lane == 0) keepbits[t] = kw;     // fire-and-forget

        // ---- OR phase: batches of 16 kept rows, 32 independent loads ----
        const u64* rowbase = mask + (u64)row0 * R;
        u64 tmp = kw;
        while (tmp) {
#define GRAB(k) int f##k = 0; u64 m##k = 0; \
            if (tmp) { f##k = (int)__builtin_ctzll(tmp); m##k = ~0ull; tmp &= tmp - 1ull; }
            GRAB(0) GRAB(1) GRAB(2) GRAB(3) GRAB(4) GRAB(5) GRAB(6) GRAB(7)
            GRAB(8) GRAB(9) GRAB(10) GRAB(11) GRAB(12) GRAB(13) GRAB(14) GRAB(15)
#undef GRAB
            // unconditional loads (sentinel f=0 masked out) -> all issue, one wait
#define LD(k) const u64* rp##k = rowbase + (unsigned)f##k * R; \
            u64 v##k = rp##k[lane]; u64 x##k = rp##k[w2];
            LD(0) LD(1) LD(2) LD(3) LD(4) LD(5) LD(6) LD(7)
            LD(8) LD(9) LD(10) LD(11) LD(12) LD(13) LD(14) LD(15)
#undef LD
            r0 |= (v0 & m0) | (v1 & m1) | (v2 & m2) | (v3 & m3)
                | (v4 & m4) | (v5 & m5) | (v6 & m6) | (v7 & m7)
                | (v8 & m8) | (v9 & m9) | (v10 & m10) | (v11 & m11)
                | (v12 & m12) | (v13 & m13) | (v14 & m14) | (v15 & m15);
            r1 |= (x0 & m0) | (x1 & m1) | (x2 & m2) | (x3 & m3)
                | (x4 & m4) | (x5 & m5) | (x6 & m6) | (x7 & m7)
                | (x8 & m8) | (x9 & m9) | (x10 & m10) | (x11 & m11)
                | (x12 & m12) | (x13 & m13) | (x14 & m14) | (x15 & m15);
        }
        d_cur = d_next;
    }
}

// ---- kernel 6: epilogue ---------------------------------------------------
__global__ void k_out(const int* __restrict__ sidx, const float* __restrict__ scores,
                      const u64* __restrict__ keepbits, float* __restrict__ out) {
    int p = blockIdx.x * blockDim.x + threadIdx.x;
    if (p < N_BOXES) {
        int orig = sidx[p];
        float s = scores[orig];
        bool k = (keepbits[p >> 6] >> (p & 63)) & 1ull;
        out[orig] = (k && (s >= CONF_THR)) ? s : 0.0f;  // writes ALL outputs (d_out poisoned)
    }
}

extern "C" void kernel_launch(void* const* d_in, const int* in_sizes, int n_in,
                              void* d_out, int out_size, void* d_ws, size_t ws_size,
                              hipStream_t stream) {
    const float* boxes  = (const float*)d_in[0];    // [6000,4]
    const float* scores = (const float*)d_in[1];    // [6000]
    float* out = (float*)d_out;                     // [6000]

    // workspace layout
    char* ws = (char*)d_ws;
    u64*    mask     = (u64*)(ws);                   // 6000*94*8 = 4,512,000 B
    u64*    diagw    = (u64*)(ws + 4512000);         // 94*64*8   =    48,128 B
    u64*    keys     = (u64*)(ws + 4560128);         // 48,000 B
    int*    rank     = (int*)(ws + 4608128);         // 24,000 B
    int*    sidx     = (int*)(ws + 4632128);         // 24,000 B
    float4* sboxes   = (float4*)(ws + 4656128);      // 96,000 B (16B aligned)
    u64*    keepbits = (u64*)(ws + 4752128);         // 752 B

    k_prep   <<<dim3(24), dim3(256), 0, stream>>>(scores, keys, rank);
    k_count  <<<dim3(24, 8), dim3(256), 0, stream>>>(keys, rank);
    k_scatter<<<dim3(24), dim3(256), 0, stream>>>(rank, (const float4*)boxes, sidx, sboxes);
    k_mask   <<<dim3(NT, NT), dim3(64), 0, stream>>>(sboxes, mask, diagw);
    k_scan   <<<dim3(1), dim3(64), 0, stream>>>(mask, diagw, keepbits);
    k_out    <<<dim3(24), dim3(256), 0, stream>>>(sidx, scores, keepbits, out);
}